// Round 2
// baseline (3126.718 us; speedup 1.0000x reference)
//
#include <hip/hip_runtime.h>

// ---- problem constants ----
constexpr int Bn = 8, Tn = 64, En = 128, Cn = 256;
constexpr int Hn = 512, Mn = 1024, NHd = 8, Dn = 32;
constexpr int NTOK = Bn * Tn * En;          // 65536 tokens
constexpr size_t SZ = (size_t)NTOK * Cn;    // 16,777,216 floats (64 MB)
constexpr int HM = NTOK / 2;                // MLP half rows
#define EPSF 1e-5f

__device__ __forceinline__ float gelu_f(float v) {
  return 0.5f * v * (1.0f + erff(v * 0.70710678118654752440f));
}

// ---------------- LayerNorm over last dim C=256, one wave per token ----------------
__global__ __launch_bounds__(256) void ln256(const float* __restrict__ src,
                                             const float* __restrict__ w,
                                             const float* __restrict__ b,
                                             float* __restrict__ dst) {
  int lane = threadIdx.x & 63;
  int tok = blockIdx.x * 4 + (threadIdx.x >> 6);
  const float4* row = (const float4*)(src + (size_t)tok * Cn);
  float4 v = row[lane];
  float s  = v.x + v.y + v.z + v.w;
  float s2 = v.x*v.x + v.y*v.y + v.z*v.z + v.w*v.w;
#pragma unroll
  for (int off = 32; off >= 1; off >>= 1) {
    s  += __shfl_xor(s, off, 64);
    s2 += __shfl_xor(s2, off, 64);
  }
  float mean = s * (1.0f / Cn);
  float var = fmaxf(s2 * (1.0f / Cn) - mean * mean, 0.0f);
  float r = rsqrtf(var + EPSF);
  float4 wv = ((const float4*)w)[lane];
  float4 bv = ((const float4*)b)[lane];
  float4 o;
  o.x = (v.x - mean) * r * wv.x + bv.x;
  o.y = (v.y - mean) * r * wv.y + bv.y;
  o.z = (v.z - mean) * r * wv.z + bv.z;
  o.w = (v.w - mean) * r * wv.w + bv.w;
  ((float4*)(dst + (size_t)tok * Cn))[lane] = o;
}

// ---------------- f32 GEMM: out[M,N] = A[M,K] @ W[K,N] (+bias, act, +res) ----------
// 128x64 tile, 256 threads, 8x4 per thread.  ACT: 0=none, 1=gelu.
template <int ACT, bool RES>
__global__ __launch_bounds__(256) void gemm128(const float* __restrict__ A,
                                               const float* __restrict__ W,
                                               const float* __restrict__ bias,
                                               const float* res,
                                               float* out,
                                               int M, int K, int N) {
  __shared__ float As[16][132];   // [k][m]
  __shared__ float Ws[16][68];    // [k][n]
  int tid = threadIdx.x;
  int tx = tid & 15, ty = tid >> 4;
  int rowBase = blockIdx.y * 128;
  int colBase = blockIdx.x * 64;
  float acc[8][4] = {};
  int lm = tid >> 1;
  int lk = (tid & 1) * 8;
  int wk = tid >> 4;
  int wn = (tid & 15) * 4;
  const float* Aload = A + (size_t)(rowBase + lm) * K + lk;
  const float* Wload = W + (size_t)wk * N + colBase + wn;
  for (int k0 = 0; k0 < K; k0 += 16) {
    float4 a0 = *(const float4*)(Aload + k0);
    float4 a1 = *(const float4*)(Aload + k0 + 4);
    float4 w4 = *(const float4*)(Wload + (size_t)k0 * N);
    As[lk + 0][lm] = a0.x; As[lk + 1][lm] = a0.y;
    As[lk + 2][lm] = a0.z; As[lk + 3][lm] = a0.w;
    As[lk + 4][lm] = a1.x; As[lk + 5][lm] = a1.y;
    As[lk + 6][lm] = a1.z; As[lk + 7][lm] = a1.w;
    *(float4*)&Ws[wk][wn] = w4;
    __syncthreads();
#pragma unroll
    for (int kk = 0; kk < 16; ++kk) {
      float a[8], b4[4];
      *(float4*)&a[0] = *(const float4*)&As[kk][ty * 8];
      *(float4*)&a[4] = *(const float4*)&As[kk][ty * 8 + 4];
      *(float4*)&b4[0] = *(const float4*)&Ws[kk][tx * 4];
#pragma unroll
      for (int i = 0; i < 8; ++i)
#pragma unroll
        for (int j = 0; j < 4; ++j) acc[i][j] += a[i] * b4[j];
    }
    __syncthreads();
  }
  float4 bias4 = make_float4(0.f, 0.f, 0.f, 0.f);
  if (bias) bias4 = *(const float4*)(bias + colBase + tx * 4);
#pragma unroll
  for (int i = 0; i < 8; ++i) {
    size_t r = rowBase + ty * 8 + i;
    float* op = out + r * N + colBase + tx * 4;
    float4 o;
    o.x = acc[i][0] + bias4.x; o.y = acc[i][1] + bias4.y;
    o.z = acc[i][2] + bias4.z; o.w = acc[i][3] + bias4.w;
    if (ACT == 1) { o.x = gelu_f(o.x); o.y = gelu_f(o.y); o.z = gelu_f(o.z); o.w = gelu_f(o.w); }
    if (RES) {
      const float4 rv = *(const float4*)(res + r * N + colBase + tx * 4);
      o.x += rv.x; o.y += rv.y; o.z += rv.z; o.w += rv.w;
    }
    *(float4*)op = o;
  }
}

// ---------------- fused spatial attention, one block per (b*T+t, head) ------------
// NOTE: o may alias q (each wave writes exactly the rows it already register-cached;
// different heads/frames touch disjoint slices).
__global__ __launch_bounds__(256) void attn_kernel(const float* q,
                                                   const float* __restrict__ k,
                                                   const float* __restrict__ v,
                                                   const int* __restrict__ adj,
                                                   float* o) {
  __shared__ float ks[128][36];
  __shared__ float vs[128][36];
  int id = blockIdx.x;
  int h = id & (NHd - 1);
  int bt = id >> 3;
  size_t base = (size_t)bt * En * Cn + h * Dn;
  int tid = threadIdx.x;
  {
    int row = tid >> 1;
    int colf = (tid & 1) * 16;
    const float4* gk = (const float4*)(k + base + (size_t)row * Cn + colf);
    const float4* gv = (const float4*)(v + base + (size_t)row * Cn + colf);
    float4* lk4 = (float4*)&ks[row][colf];
    float4* lv4 = (float4*)&vs[row][colf];
#pragma unroll
    for (int i = 0; i < 4; ++i) { lk4[i] = gk[i]; lv4[i] = gv[i]; }
  }
  int e = tid >> 1;
  int half = tid & 1;
  float qr[32];
  {
    const float4* gq = (const float4*)(q + base + (size_t)e * Cn);
#pragma unroll
    for (int i = 0; i < 8; ++i) ((float4*)qr)[i] = gq[i];
  }
  __syncthreads();
  float acc[32] = {};
  for (int i = 0; i < 64; ++i) {
    int f = half * 64 + i;
    float s = 0.f;
#pragma unroll
    for (int d = 0; d < 32; d += 4) {
      float4 kv = *(const float4*)&ks[f][d];
      s += qr[d] * kv.x + qr[d + 1] * kv.y + qr[d + 2] * kv.z + qr[d + 3] * kv.w;
    }
    float m = (float)adj[e * En + f];
    s = (s * m + 1.0f) * 0.5f;
#pragma unroll
    for (int d = 0; d < 32; d += 4) {
      float4 vv = *(const float4*)&vs[f][d];
      acc[d] += s * vv.x; acc[d + 1] += s * vv.y;
      acc[d + 2] += s * vv.z; acc[d + 3] += s * vv.w;
    }
  }
#pragma unroll
  for (int d = 0; d < 32; ++d) acc[d] += __shfl_xor(acc[d], 1, 64);
  if (half == 0) {
    float* op = o + base + (size_t)e * Cn;
#pragma unroll
    for (int d = 0; d < 32; d += 4)
      *(float4*)(op + d) = make_float4(acc[d], acc[d + 1], acc[d + 2], acc[d + 3]);
  }
}

// ---------------- residual 1 (IN-PLACE on xs): x1 = x + xs + gamma_s * p2 ----------
__global__ __launch_bounds__(256) void resid1_kernel(const float4* x,
                                                     float4* xs_x1,
                                                     const float4* p2,
                                                     const float* gs) {
  size_t i = (size_t)blockIdx.x * 256 + threadIdx.x;
  float g = gs[0];
  float4 a = x[i], s4 = xs_x1[i], o4 = p2[i], r;
  r.x = a.x + s4.x + g * o4.x;
  r.y = a.y + s4.y + g * o4.y;
  r.z = a.z + s4.z + g * o4.z;
  r.w = a.w + s4.w + g * o4.w;
  xs_x1[i] = r;
}

// ---------------- weight transposes ------------------------------------------------
__global__ __launch_bounds__(256) void transpose_w1(const float* __restrict__ w1,
                                                    float* __restrict__ w1T) {
  int idx = blockIdx.x * 256 + threadIdx.x;   // over H*C*3
  int h = idx & 511, ck = idx >> 9;
  w1T[idx] = w1[(size_t)h * (Cn * 3) + ck];   // w1T[(c*3+dt)*H + h]
}
__global__ __launch_bounds__(256) void transpose_w2(const float* __restrict__ w2,
                                                    float* __restrict__ w2T) {
  int idx = blockIdx.x * 256 + threadIdx.x;   // over H*C
  int c = idx & 255, h = idx >> 8;
  w2T[idx] = w2[(size_t)c * Hn + h];          // w2T[h*C + c]
}

// ---------------- conv1 (k=3, pad=1) + BN1 + GELU, one block per (b,e) -------------
// LDS: 128x68 floats = 34 KB (c tiled in 2 chunks of 128).
__global__ __launch_bounds__(512) void conv1_kernel(const float* __restrict__ xt,
                                                    const float* __restrict__ w1T,
                                                    const float* __restrict__ bn1w,
                                                    const float* __restrict__ bn1b,
                                                    const float* __restrict__ bn1m,
                                                    const float* __restrict__ bn1v,
                                                    float* __restrict__ y1) {
  __shared__ float xls[128][68];   // [c_local][t_phys], t_phys = t+1; rows 0,65 zero
  int be = blockIdx.x;
  int b = be >> 7, e = be & 127;
  int tid = threadIdx.x;           // = h
  const size_t xbase = ((size_t)b * Tn * En + e) * Cn;
  float s1 = bn1w[tid] * rsqrtf(bn1v[tid] + EPSF);
  float o1 = bn1b[tid] - bn1m[tid] * s1;
  float acc[4][16] = {};
  for (int cc = 0; cc < 2; ++cc) {
    __syncthreads();
#pragma unroll
    for (int i = 0; i < 4; ++i) {
      int f = i * 512 + tid;          // 0..2047 float4 slots (64 t x 32 c4)
      int t = f >> 5;
      int c4 = (f & 31) << 2;
      float4 xv = *(const float4*)(xt + xbase + (size_t)t * En * Cn + cc * 128 + c4);
      xls[c4 + 0][t + 1] = xv.x; xls[c4 + 1][t + 1] = xv.y;
      xls[c4 + 2][t + 1] = xv.z; xls[c4 + 3][t + 1] = xv.w;
    }
    if (tid < 128) { xls[tid][0] = 0.f; xls[tid][65] = 0.f; }
    __syncthreads();
    for (int c = 0; c < 128; ++c) {
      int cg = cc * 128 + c;
      float w0  = w1T[(size_t)(cg * 3 + 0) * Hn + tid];
      float w1v = w1T[(size_t)(cg * 3 + 1) * Hn + tid];
      float w2v = w1T[(size_t)(cg * 3 + 2) * Hn + tid];
#pragma unroll
      for (int tb = 0; tb < 4; ++tb) {
        const float* row = &xls[c][tb * 16];
        float xr[18];
#pragma unroll
        for (int i2 = 0; i2 < 4; ++i2) ((float4*)xr)[i2] = ((const float4*)row)[i2];
        xr[16] = row[16]; xr[17] = row[17];
#pragma unroll
        for (int j = 0; j < 16; ++j)
          acc[tb][j] += xr[j] * w0 + xr[j + 1] * w1v + xr[j + 2] * w2v;
      }
    }
  }
  size_t ybase = (size_t)be * Tn * Hn + tid;
#pragma unroll
  for (int tb = 0; tb < 4; ++tb)
#pragma unroll
    for (int j = 0; j < 16; ++j) {
      float val = acc[tb][j] * s1 + o1;
      y1[ybase + (size_t)(tb * 16 + j) * Hn] = gelu_f(val);
    }
}

// ---------------- conv2 (1x1) + BN2 + temporal residual, one block per (b,e) -------
// LDS: 64x132 floats = 33 KB (h tiled in 4 chunks of 128).
// x2 = 2*x1 + gamma_t * bn2(conv2(y1))
__global__ __launch_bounds__(256) void conv2_kernel(const float* __restrict__ y1,
                                                    const float* __restrict__ w2T,
                                                    const float* __restrict__ bn2w,
                                                    const float* __restrict__ bn2b,
                                                    const float* __restrict__ bn2m,
                                                    const float* __restrict__ bn2v,
                                                    const float* __restrict__ gamma_t,
                                                    const float* __restrict__ x1,
                                                    float* __restrict__ x2) {
  __shared__ float yt[64][132];    // [t][h_local]
  int be = blockIdx.x;
  int b = be >> 7, e = be & 127;
  int tid = threadIdx.x;           // = c
  float s2 = bn2w[tid] * rsqrtf(bn2v[tid] + EPSF);
  float o2 = bn2b[tid] - bn2m[tid] * s2;
  float gt = gamma_t[0];
  float acc[64] = {};
  for (int hc = 0; hc < 4; ++hc) {
    __syncthreads();
#pragma unroll
    for (int i = 0; i < 8; ++i) {
      int f = i * 256 + tid;        // 0..2047 float4 slots (64 t x 32 h4)
      int t = f >> 5;
      int h4 = (f & 31) << 2;
      float4 yv = *(const float4*)(y1 + (size_t)be * Tn * Hn + (size_t)t * Hn + hc * 128 + h4);
      *(float4*)&yt[t][h4] = yv;
    }
    __syncthreads();
    for (int hb = 0; hb < 4; ++hb) {
      int h0 = hb * 32;
      float wr[32];
#pragma unroll
      for (int j = 0; j < 32; ++j) wr[j] = w2T[(size_t)(hc * 128 + h0 + j) * Cn + tid];
#pragma unroll
      for (int t = 0; t < 64; ++t) {
        const float4* yr = (const float4*)&yt[t][h0];
        float p0 = 0.f, p1 = 0.f, p2v = 0.f, p3 = 0.f;
#pragma unroll
        for (int j4 = 0; j4 < 8; ++j4) {
          float4 yv = yr[j4];
          p0  += yv.x * wr[j4 * 4 + 0];
          p1  += yv.y * wr[j4 * 4 + 1];
          p2v += yv.z * wr[j4 * 4 + 2];
          p3  += yv.w * wr[j4 * 4 + 3];
        }
        acc[t] += (p0 + p1) + (p2v + p3);
      }
    }
  }
  size_t obase = ((size_t)b * Tn * En + e) * Cn + tid;
#pragma unroll
  for (int t = 0; t < 64; ++t) {
    size_t idx = obase + (size_t)t * En * Cn;
    x2[idx] = 2.0f * x1[idx] + gt * (acc[t] * s2 + o2);
  }
}

// ---------------- host-side launch --------------------------------------------------
extern "C" void kernel_launch(void* const* d_in, const int* in_sizes, int n_in,
                              void* d_out, int out_size, void* d_ws, size_t ws_size,
                              hipStream_t stream) {
  (void)in_sizes; (void)n_in; (void)out_size; (void)ws_size;
  const float* x       = (const float*)d_in[0];
  const int*   adj     = (const int*)  d_in[1];
  const float* n1_w    = (const float*)d_in[2];
  const float* n1_b    = (const float*)d_in[3];
  const float* q_w     = (const float*)d_in[4];
  const float* k_w     = (const float*)d_in[5];
  const float* v_w     = (const float*)d_in[6];
  const float* proj_w  = (const float*)d_in[7];
  const float* proj_b  = (const float*)d_in[8];
  const float* on_w    = (const float*)d_in[9];
  const float* on_b    = (const float*)d_in[10];
  const float* gamma_s = (const float*)d_in[11];
  const float* conv1_w = (const float*)d_in[12];
  const float* bn1_w   = (const float*)d_in[13];
  const float* bn1_b   = (const float*)d_in[14];
  const float* bn1_m   = (const float*)d_in[15];
  const float* bn1_v   = (const float*)d_in[16];
  const float* conv2_w = (const float*)d_in[17];
  const float* bn2_w   = (const float*)d_in[18];
  const float* bn2_b   = (const float*)d_in[19];
  const float* bn2_m   = (const float*)d_in[20];
  const float* bn2_v   = (const float*)d_in[21];
  const float* tn_w    = (const float*)d_in[22];
  const float* tn_b    = (const float*)d_in[23];
  const float* gamma_t = (const float*)d_in[24];
  const float* n3_w    = (const float*)d_in[25];
  const float* n3_b    = (const float*)d_in[26];
  const float* fc1_w   = (const float*)d_in[27];
  const float* fc1_b   = (const float*)d_in[28];
  const float* fc2_w   = (const float*)d_in[29];
  const float* fc2_b   = (const float*)d_in[30];
  float* O = (float*)d_out;           // also used as scratch (v -> xt -> x2)

  // workspace: 3*SZ + transposed weights = ~194 MB
  float* ws  = (float*)d_ws;
  float* A   = ws;             // xs -> x1 (in place) -> xm
  float* Bb  = ws + SZ;        // q -> o -> y1(lo) -> h(half, 2SZ with C)
  float* Cc  = ws + 2 * SZ;    // k -> pb/p2 src -> y1(hi)
  float* w1T = ws + 3 * SZ;                          // 393216 floats
  float* w2T = ws + 3 * SZ + (size_t)Hn * Cn * 3;    // 131072 floats

  transpose_w1<<<(Hn * Cn * 3) / 256, 256, 0, stream>>>(conv1_w, w1T);
  transpose_w2<<<(Hn * Cn) / 256, 256, 0, stream>>>(conv2_w, w2T);

  // ---- spatial attention branch ----
  ln256<<<NTOK / 4, 256, 0, stream>>>(x, n1_w, n1_b, A);                       // A = xs
  gemm128<0, false><<<dim3(Cn / 64, NTOK / 128), 256, 0, stream>>>(A, q_w, nullptr, nullptr, Bb, NTOK, Cn, Cn);
  gemm128<0, false><<<dim3(Cn / 64, NTOK / 128), 256, 0, stream>>>(A, k_w, nullptr, nullptr, Cc, NTOK, Cn, Cn);
  gemm128<0, false><<<dim3(Cn / 64, NTOK / 128), 256, 0, stream>>>(A, v_w, nullptr, nullptr, O, NTOK, Cn, Cn);
  attn_kernel<<<Bn * Tn * NHd, 256, 0, stream>>>(Bb, Cc, O, adj, Bb);          // o over q
  gemm128<0, false><<<dim3(Cn / 64, NTOK / 128), 256, 0, stream>>>(Bb, proj_w, proj_b, nullptr, Cc, NTOK, Cn, Cn);
  ln256<<<NTOK / 4, 256, 0, stream>>>(Cc, on_w, on_b, O);                      // O = p2
  resid1_kernel<<<(int)(SZ / (4 * 256)), 256, 0, stream>>>((const float4*)x, (float4*)A,
                                                           (const float4*)O, gamma_s);  // A = x1
  // ---- temporal conv branch ----
  ln256<<<NTOK / 4, 256, 0, stream>>>(A, tn_w, tn_b, O);                       // O = xt
  conv1_kernel<<<Bn * En, 512, 0, stream>>>(O, w1T, bn1_w, bn1_b, bn1_m, bn1_v, Bb);   // Bb|Cc = y1 (2 SZ)
  conv2_kernel<<<Bn * En, 256, 0, stream>>>(Bb, w2T, bn2_w, bn2_b, bn2_m, bn2_v, gamma_t, A, O);  // O = x2
  // ---- MLP (split in two halves so hidden fits 2*SZ region Bb|Cc) ----
  ln256<<<NTOK / 4, 256, 0, stream>>>(O, n3_w, n3_b, A);                       // A = xm
  for (int p = 0; p < 2; ++p) {
    const float* xm_p = A + (size_t)p * HM * Cn;
    float* res_p = O + (size_t)p * HM * Cn;
    gemm128<1, false><<<dim3(Mn / 64, HM / 128), 256, 0, stream>>>(xm_p, fc1_w, fc1_b, nullptr, Bb, HM, Cn, Mn);
    gemm128<0, true><<<dim3(Cn / 64, HM / 128), 256, 0, stream>>>(Bb, fc2_w, fc2_b, res_p, res_p, HM, Mn, Cn);
  }
}

// Round 3
// 940.549 us; speedup vs baseline: 3.3244x; 3.3244x over previous
//
#include <hip/hip_runtime.h>
#include <cstdint>

// ---- problem constants ----
constexpr int Bn = 8, Tn = 64, En = 128, Cn = 256;
constexpr int Hn = 512, Mn = 1024, NHd = 8, Dn = 32;
constexpr int NTOK = Bn * Tn * En;          // 65536 tokens
constexpr size_t SZ = (size_t)NTOK * Cn;    // 16,777,216 elements
#define EPSF 1e-5f

typedef __attribute__((ext_vector_type(8))) short short8;
typedef __attribute__((ext_vector_type(4))) float f32x4;

__device__ __forceinline__ float bf2f(unsigned short u) {
  union { unsigned int i; float f; } c; c.i = ((unsigned int)u) << 16; return c.f;
}
__device__ __forceinline__ unsigned short f2bf(float f) {
  union { float f; unsigned int i; } c; c.f = f;
  unsigned int u = c.i;
  return (unsigned short)((u + 0x7fffu + ((u >> 16) & 1u)) >> 16);
}
__device__ __forceinline__ float gelu_f(float v) {
  return 0.5f * v * (1.0f + erff(v * 0.70710678118654752440f));
}

// async global->LDS, 16B per lane; lds dest = wave-uniform base + lane*16
__device__ __forceinline__ void gload16(const unsigned short* g, unsigned short* l) {
  __builtin_amdgcn_global_load_lds(
      (const __attribute__((address_space(1))) unsigned int*)g,
      (__attribute__((address_space(3))) unsigned int*)l, 16, 0, 0);
}

// ---------------- MFMA GEMM: out[M,N] = A[M,K](bf16) @ Bt[N,K]^T (bf16) ------------
// 128x128 tile, BK=32, 256 threads (4 waves, each 64x64 via 4x4 16x16 frags).
// EPI: 0 = bf16 plain; 1 = bf16 +bias; 2 = bf16 gelu(acc*scale+bias);
//      3 = f32 2*res + g*(acc*scale+bias); 4 = f32 res + acc + bias;
//      5 = f32 acc + bias.
// C1A: conv1 A-addressing over t-padded buffer [b][66][e][c], slab = k0>>8.
template <int EPI, bool C1A>
__global__ __launch_bounds__(256) void mfma_gemm(
    const unsigned short* __restrict__ A,
    const unsigned short* __restrict__ Bt,
    const float* __restrict__ scale,
    const float* __restrict__ bias,
    const float* __restrict__ resf,
    const float* __restrict__ gscal,
    void* __restrict__ outv,
    int K, int N) {
  __shared__ unsigned short As[128 * 32];
  __shared__ unsigned short Bs[128 * 32];
  int tid = threadIdx.x;
  int lane = tid & 63, wave = tid >> 6;
  int mtile = blockIdx.y, ntile = blockIdx.x;
  int rowBase = mtile * 128;
  int colBase = ntile * 128;
  int lda = C1A ? 256 : K;
  int r0 = lane >> 2;            // 0..15 row within 16-row chunk
  int c0 = (lane & 3) * 8;       // k-chunk (elements)
  f32x4 acc[4][4];
#pragma unroll
  for (int i = 0; i < 4; ++i)
#pragma unroll
    for (int j = 0; j < 4; ++j) acc[i][j] = (f32x4)(0.0f);
  int mbase = (wave >> 1) * 64;
  int nbase = (wave & 1) * 64;
  int arow = lane & 15;
  int akk = (lane >> 4) * 8;

  for (int k0 = 0; k0 < K; k0 += 32) {
    size_t arowb; int kin;
    if (C1A) {
      int bb = mtile >> 6, tt = mtile & 63;
      int slab = k0 >> 8;                       // 0,1,2  <-> dt = slab-1
      arowb = (size_t)((bb * 66 + tt + slab) * 128);
      kin = k0 & 255;
    } else {
      arowb = (size_t)rowBase;
      kin = k0;
    }
#pragma unroll
    for (int i = 0; i < 2; ++i) {
      int q = i * 4 + wave;                     // 16-row chunk id, 0..7
      const unsigned short* gp = A + (arowb + q * 16 + r0) * (size_t)lda + kin + c0;
      gload16(gp, &As[q * 512]);
      const unsigned short* gq = Bt + ((size_t)colBase + q * 16 + r0) * (size_t)K + k0 + c0;
      gload16(gq, &Bs[q * 512]);
    }
    __syncthreads();
    short8 af[4], bf[4];
#pragma unroll
    for (int i = 0; i < 4; ++i)
      af[i] = *(const short8*)&As[(mbase + i * 16 + arow) * 32 + akk];
#pragma unroll
    for (int j = 0; j < 4; ++j)
      bf[j] = *(const short8*)&Bs[(nbase + j * 16 + arow) * 32 + akk];
#pragma unroll
    for (int i = 0; i < 4; ++i)
#pragma unroll
      for (int j = 0; j < 4; ++j)
        acc[i][j] = __builtin_amdgcn_mfma_f32_16x16x32_bf16(af[i], bf[j], acc[i][j], 0, 0, 0);
    __syncthreads();
  }

  int crow0 = (lane >> 4) * 4;
  int ccol = lane & 15;
  float gt = (EPI == 3) ? gscal[0] : 0.f;
#pragma unroll
  for (int i = 0; i < 4; ++i) {
#pragma unroll
    for (int j = 0; j < 4; ++j) {
      int col = colBase + nbase + j * 16 + ccol;
      float sc = 1.f, bi = 0.f;
      if (EPI >= 1 && bias) bi = bias[col];
      if ((EPI == 2 || EPI == 3) && scale) sc = scale[col];
#pragma unroll
      for (int r = 0; r < 4; ++r) {
        size_t row = (size_t)rowBase + mbase + i * 16 + crow0 + r;
        size_t idx = row * (size_t)N + col;
        float v = acc[i][j][r];
        if (EPI == 0)      ((unsigned short*)outv)[idx] = f2bf(v);
        else if (EPI == 1) ((unsigned short*)outv)[idx] = f2bf(v + bi);
        else if (EPI == 2) ((unsigned short*)outv)[idx] = f2bf(gelu_f(v * sc + bi));
        else if (EPI == 3) ((float*)outv)[idx] = 2.0f * resf[idx] + gt * (v * sc + bi);
        else if (EPI == 4) ((float*)outv)[idx] = resf[idx] + v + bi;
        else if (EPI == 5) ((float*)outv)[idx] = v + bi;
      }
    }
  }
}

// ---------------- LayerNorm f32 -> bf16, one wave per token ------------------------
template <bool PAD>
__global__ __launch_bounds__(256) void ln256_bf(const float* __restrict__ src,
                                                const float* __restrict__ w,
                                                const float* __restrict__ b,
                                                unsigned short* __restrict__ dst) {
  int lane = threadIdx.x & 63;
  int tok = blockIdx.x * 4 + (threadIdx.x >> 6);
  const float4* row = (const float4*)(src + (size_t)tok * Cn);
  float4 v = row[lane];
  float s  = v.x + v.y + v.z + v.w;
  float s2 = v.x*v.x + v.y*v.y + v.z*v.z + v.w*v.w;
#pragma unroll
  for (int off = 32; off >= 1; off >>= 1) {
    s  += __shfl_xor(s, off, 64);
    s2 += __shfl_xor(s2, off, 64);
  }
  float mean = s * (1.0f / Cn);
  float var = fmaxf(s2 * (1.0f / Cn) - mean * mean, 0.0f);
  float r = rsqrtf(var + EPSF);
  float4 wv = ((const float4*)w)[lane];
  float4 bv = ((const float4*)b)[lane];
  size_t dtok = tok;
  if (PAD) {
    int bb = tok >> 13, tt = (tok >> 7) & 63, e = tok & 127;
    dtok = ((size_t)(bb * 66 + tt + 1)) * 128 + e;
  }
  ushort4 o;
  o.x = f2bf((v.x - mean) * r * wv.x + bv.x);
  o.y = f2bf((v.y - mean) * r * wv.y + bv.y);
  o.z = f2bf((v.z - mean) * r * wv.z + bv.z);
  o.w = f2bf((v.w - mean) * r * wv.w + bv.w);
  *(ushort4*)(dst + dtok * Cn + lane * 4) = o;
}

// ---------------- fused spatial attention (vector, bf16 in/out) --------------------
__global__ __launch_bounds__(256) void attn_kernel(const unsigned short* __restrict__ qkv,
                                                   const int* __restrict__ adj,
                                                   unsigned short* __restrict__ o) {
  __shared__ float ks[128][36];
  __shared__ float vs[128][36];
  int id = blockIdx.x;
  int h = id & (NHd - 1);
  int bt = id >> 3;
  int tid = threadIdx.x;
  {
    int row = tid >> 1;
    int colf = (tid & 1) * 16;
    size_t gbase = ((size_t)bt * 128 + row) * 768 + h * 32 + colf;
    const unsigned short* gk = qkv + gbase + 256;
    const unsigned short* gv = qkv + gbase + 512;
#pragma unroll
    for (int p = 0; p < 2; ++p) {
      short8 kv = *(const short8*)(gk + p * 8);
      short8 vv = *(const short8*)(gv + p * 8);
#pragma unroll
      for (int j = 0; j < 8; ++j) {
        ks[row][colf + p * 8 + j] = bf2f((unsigned short)kv[j]);
        vs[row][colf + p * 8 + j] = bf2f((unsigned short)vv[j]);
      }
    }
  }
  int e = tid >> 1;
  int half = tid & 1;
  float qr[32];
  {
    const unsigned short* gq = qkv + ((size_t)bt * 128 + e) * 768 + h * 32;
#pragma unroll
    for (int p = 0; p < 4; ++p) {
      short8 qv = *(const short8*)(gq + p * 8);
#pragma unroll
      for (int j = 0; j < 8; ++j) qr[p * 8 + j] = bf2f((unsigned short)qv[j]);
    }
  }
  __syncthreads();
  float acc[32] = {};
  for (int i = 0; i < 64; ++i) {
    int f = half * 64 + i;
    float s = 0.f;
#pragma unroll
    for (int d = 0; d < 32; ++d) s += qr[d] * ks[f][d];
    float m = (float)adj[e * En + f];
    s = (s * m + 1.0f) * 0.5f;
#pragma unroll
    for (int d = 0; d < 32; ++d) acc[d] += s * vs[f][d];
  }
#pragma unroll
  for (int d = 0; d < 32; ++d) acc[d] += __shfl_xor(acc[d], 1, 64);
  if (half == 0) {
    unsigned short* op = o + ((size_t)bt * 128 + e) * 256 + h * 32;
#pragma unroll
    for (int d = 0; d < 32; ++d) op[d] = f2bf(acc[d]);
  }
}

// ---------------- residual 1: x1 = x + xs + gamma_s * p2 (f32 out) -----------------
__global__ __launch_bounds__(256) void resid1_kernel(const float* __restrict__ x,
                                                     const unsigned short* __restrict__ xs,
                                                     const unsigned short* __restrict__ p2,
                                                     const float* __restrict__ gs,
                                                     float* __restrict__ x1) {
  size_t i = ((size_t)blockIdx.x * 256 + threadIdx.x) * 4;
  float g = gs[0];
  float4 xv = *(const float4*)(x + i);
  ushort4 s4 = *(const ushort4*)(xs + i);
  ushort4 p4 = *(const ushort4*)(p2 + i);
  float4 r;
  r.x = xv.x + bf2f(s4.x) + g * bf2f(p4.x);
  r.y = xv.y + bf2f(s4.y) + g * bf2f(p4.y);
  r.z = xv.z + bf2f(s4.z) + g * bf2f(p4.z);
  r.w = xv.w + bf2f(s4.w) + g * bf2f(p4.w);
  *(float4*)(x1 + i) = r;
}

// ---------------- prep kernels -----------------------------------------------------
__global__ __launch_bounds__(256) void transcast(const float* __restrict__ src,
                                                 unsigned short* __restrict__ dst,
                                                 int N, int K) {   // dst[n*K+k] = src[k*N+n]
  int idx = blockIdx.x * 256 + threadIdx.x;
  int n = idx / K, k = idx - n * K;
  dst[idx] = f2bf(src[(size_t)k * N + n]);
}
__global__ __launch_bounds__(256) void castbf(const float* __restrict__ s,
                                              unsigned short* __restrict__ d) {
  int i = blockIdx.x * 256 + threadIdx.x;
  d[i] = f2bf(s[i]);
}
__global__ __launch_bounds__(256) void pack_conv1(const float* __restrict__ w1,
                                                  unsigned short* __restrict__ dst) {
  int idx = blockIdx.x * 256 + threadIdx.x;   // 512*768: [h][slab*256+c]
  int hh = idx / 768, kk = idx - hh * 768;
  int slab = kk >> 8, c = kk & 255;
  dst[idx] = f2bf(w1[(size_t)hh * 768 + c * 3 + slab]);
}
__global__ __launch_bounds__(256) void bnfold(const float* __restrict__ w,
                                              const float* __restrict__ bvec,
                                              const float* __restrict__ m,
                                              const float* __restrict__ v,
                                              float* __restrict__ s,
                                              float* __restrict__ o, int n) {
  int i = blockIdx.x * 256 + threadIdx.x;
  if (i < n) {
    float sc = w[i] * rsqrtf(v[i] + EPSF);
    s[i] = sc;
    o[i] = bvec[i] - m[i] * sc;
  }
}
__global__ __launch_bounds__(256) void zero_pad(unsigned short* __restrict__ xt) {
  int idx = blockIdx.x * 256 + threadIdx.x;   // 8 b * 2 rows * 128*256
  int bb = idx >> 16;
  int rem = idx & 65535;
  int which = rem >> 15;      // 0 -> t_pad 0, 1 -> t_pad 65
  int off = rem & 32767;
  size_t base = ((size_t)(bb * 66 + which * 65)) * 128 * 256;
  xt[base + off] = 0;
}

// ---------------- host-side launch --------------------------------------------------
extern "C" void kernel_launch(void* const* d_in, const int* in_sizes, int n_in,
                              void* d_out, int out_size, void* d_ws, size_t ws_size,
                              hipStream_t stream) {
  (void)in_sizes; (void)n_in; (void)out_size; (void)ws_size;
  const float* x       = (const float*)d_in[0];
  const int*   adj     = (const int*)  d_in[1];
  const float* n1_w    = (const float*)d_in[2];
  const float* n1_b    = (const float*)d_in[3];
  const float* q_w     = (const float*)d_in[4];
  const float* k_w     = (const float*)d_in[5];
  const float* v_w     = (const float*)d_in[6];
  const float* proj_w  = (const float*)d_in[7];
  const float* proj_b  = (const float*)d_in[8];
  const float* on_w    = (const float*)d_in[9];
  const float* on_b    = (const float*)d_in[10];
  const float* gamma_s = (const float*)d_in[11];
  const float* conv1_w = (const float*)d_in[12];
  const float* bn1_w   = (const float*)d_in[13];
  const float* bn1_b   = (const float*)d_in[14];
  const float* bn1_m   = (const float*)d_in[15];
  const float* bn1_v   = (const float*)d_in[16];
  const float* conv2_w = (const float*)d_in[17];
  const float* bn2_w   = (const float*)d_in[18];
  const float* bn2_b   = (const float*)d_in[19];
  const float* bn2_m   = (const float*)d_in[20];
  const float* bn2_v   = (const float*)d_in[21];
  const float* tn_w    = (const float*)d_in[22];
  const float* tn_b    = (const float*)d_in[23];
  const float* gamma_t = (const float*)d_in[24];
  const float* n3_w    = (const float*)d_in[25];
  const float* n3_b    = (const float*)d_in[26];
  const float* fc1_w   = (const float*)d_in[27];
  const float* fc1_b   = (const float*)d_in[28];
  const float* fc2_w   = (const float*)d_in[29];
  const float* fc2_b   = (const float*)d_in[30];
  float* O = (float*)d_out;

  const size_t MB = 1024 * 1024;
  char* wsb = (char*)d_ws;
  // live-range overlaid buffers (peak ~167 MB)
  unsigned short* qkvb = (unsigned short*)(wsb + 0);        // 96 MB  [qkv gemm -> attn]
  float*          pjo  = (float*)(wsb + 0);                 // 64 MB  [proj out f32]
  float*          x1b  = (float*)(wsb + 0);                 // 64 MB  [resid1 -> conv2]
  unsigned short* xmb  = (unsigned short*)(wsb + 0);        // 32 MB  [ln3 -> fc1]
  unsigned short* hb   = (unsigned short*)(wsb + 32 * MB);  // 128 MB [fc1 -> fc2]
  unsigned short* xtp  = (unsigned short*)(wsb + 64 * MB);  // 33 MB  [ln_t -> conv1]
  unsigned short* xsb  = (unsigned short*)(wsb + 96 * MB);  // 32 MB  [ln1 -> resid1]
  unsigned short* oat  = (unsigned short*)(wsb + 128 * MB); // 32 MB  [attn -> proj]
  unsigned short* p2b  = (unsigned short*)(wsb + 128 * MB); // 32 MB  [ln_o -> resid1]
  unsigned short* y1b  = (unsigned short*)(wsb + 100 * MB); // 64 MB  [conv1 -> conv2]
  char* wp = wsb + 164 * MB;
  unsigned short* Wqkv = (unsigned short*)wp;  wp += 768 * 256 * 2;
  unsigned short* PjT  = (unsigned short*)wp;  wp += 256 * 256 * 2;
  unsigned short* W1t  = (unsigned short*)wp;  wp += 512 * 768 * 2;
  unsigned short* W2t  = (unsigned short*)wp;  wp += 256 * 512 * 2;
  unsigned short* F1t  = (unsigned short*)wp;  wp += 1024 * 256 * 2;
  unsigned short* F2t  = (unsigned short*)wp;  wp += 256 * 1024 * 2;
  float* s1 = (float*)wp; wp += 512 * 4;
  float* o1 = (float*)wp; wp += 512 * 4;
  float* s2 = (float*)wp; wp += 256 * 4;
  float* o2 = (float*)wp; wp += 256 * 4;

  // ---- prep (cheap, once per launch) ----
  transcast<<<768 * 256 / 256, 256, 0, stream>>>(q_w, Wqkv, 256, 256);
  transcast<<<768 * 256 / 256, 256, 0, stream>>>(k_w, Wqkv + 256 * 256, 256, 256);
  transcast<<<768 * 256 / 256, 256, 0, stream>>>(v_w, Wqkv + 512 * 256, 256, 256);
  transcast<<<256 * 256 / 256, 256, 0, stream>>>(proj_w, PjT, 256, 256);
  pack_conv1<<<512 * 768 / 256, 256, 0, stream>>>(conv1_w, W1t);
  castbf<<<256 * 512 / 256, 256, 0, stream>>>(conv2_w, W2t);   // already [C][H] = [N][K]
  transcast<<<1024 * 256 / 256, 256, 0, stream>>>(fc1_w, F1t, 1024, 256);
  transcast<<<256 * 1024 / 256, 256, 0, stream>>>(fc2_w, F2t, 256, 1024);
  bnfold<<<2, 256, 0, stream>>>(bn1_w, bn1_b, bn1_m, bn1_v, s1, o1, 512);
  bnfold<<<1, 256, 0, stream>>>(bn2_w, bn2_b, bn2_m, bn2_v, s2, o2, 256);
  zero_pad<<<524288 / 256, 256, 0, stream>>>(xtp);

  // ---- spatial attention branch ----
  ln256_bf<false><<<NTOK / 4, 256, 0, stream>>>(x, n1_w, n1_b, xsb);
  mfma_gemm<0, false><<<dim3(6, 512), 256, 0, stream>>>(xsb, Wqkv, nullptr, nullptr, nullptr, nullptr, qkvb, 256, 768);
  attn_kernel<<<Bn * Tn * NHd, 256, 0, stream>>>(qkvb, adj, oat);
  mfma_gemm<5, false><<<dim3(2, 512), 256, 0, stream>>>(oat, PjT, nullptr, proj_b, nullptr, nullptr, pjo, 256, 256);
  ln256_bf<false><<<NTOK / 4, 256, 0, stream>>>(pjo, on_w, on_b, p2b);
  resid1_kernel<<<(int)(SZ / (4 * 256)), 256, 0, stream>>>(x, xsb, p2b, gamma_s, x1b);

  // ---- temporal conv branch ----
  ln256_bf<true><<<NTOK / 4, 256, 0, stream>>>(x1b, tn_w, tn_b, xtp);
  mfma_gemm<2, true><<<dim3(4, 512), 256, 0, stream>>>(xtp, W1t, s1, o1, nullptr, nullptr, y1b, 768, 512);
  mfma_gemm<3, false><<<dim3(2, 512), 256, 0, stream>>>(y1b, W2t, s2, o2, x1b, gamma_t, O, 512, 256);

  // ---- MLP ----
  ln256_bf<false><<<NTOK / 4, 256, 0, stream>>>(O, n3_w, n3_b, xmb);
  mfma_gemm<2, false><<<dim3(8, 512), 256, 0, stream>>>(xmb, F1t, nullptr, fc1_b, nullptr, nullptr, hb, 256, 1024);
  mfma_gemm<4, false><<<dim3(2, 512), 256, 0, stream>>>(hb, F2t, nullptr, fc2_b, O, nullptr, O, 1024, 256);
}

// Round 4
// 741.992 us; speedup vs baseline: 4.2140x; 1.2676x over previous
//
#include <hip/hip_runtime.h>
#include <cstdint>

// ---- problem constants ----
constexpr int Bn = 8, Tn = 64, En = 128, Cn = 256;
constexpr int Hn = 512, Mn = 1024, NHd = 8, Dn = 32;
constexpr int NTOK = Bn * Tn * En;          // 65536 tokens
constexpr size_t SZ = (size_t)NTOK * Cn;    // 16,777,216 elements
#define EPSF 1e-5f

typedef __attribute__((ext_vector_type(8))) short short8;
typedef __attribute__((ext_vector_type(4))) float f32x4;

__device__ __forceinline__ float bf2f(unsigned short u) {
  union { unsigned int i; float f; } c; c.i = ((unsigned int)u) << 16; return c.f;
}
__device__ __forceinline__ unsigned short f2bf(float f) {
  union { float f; unsigned int i; } c; c.f = f;
  unsigned int u = c.i;
  return (unsigned short)((u + 0x7fffu + ((u >> 16) & 1u)) >> 16);
}
__device__ __forceinline__ float gelu_f(float v) {
  return 0.5f * v * (1.0f + erff(v * 0.70710678118654752440f));
}

// async global->LDS, 16B per lane; lds dest = wave-uniform base + lane*16
__device__ __forceinline__ void gload16(const unsigned short* g, unsigned short* l) {
  __builtin_amdgcn_global_load_lds(
      (const __attribute__((address_space(1))) unsigned int*)g,
      (__attribute__((address_space(3))) unsigned int*)l, 16, 0, 0);
}

// ---------------- MFMA GEMM: out[M,N] = A[M,K](bf16) @ Bt[N,K]^T (bf16) ------------
// 128x128 tile, BK=32, 256 threads (4 waves, each 64x64 via 4x4 16x16 frags).
// EPI: 0 = bf16 plain; 1 = bf16 +bias; 2 = bf16 gelu(acc*scale+bias);
//      3 = f32 2*res + g*(acc*scale+bias); 4 = f32 res + acc + bias;
//      5 = f32 acc + bias.
// C1A: conv1 A-addressing over t-padded buffer [b][66][e][c], slab = k0>>8.
template <int EPI, bool C1A>
__global__ __launch_bounds__(256) void mfma_gemm(
    const unsigned short* __restrict__ A,
    const unsigned short* __restrict__ Bt,
    const float* __restrict__ scale,
    const float* __restrict__ bias,
    const float* __restrict__ resf,
    const float* __restrict__ gscal,
    void* __restrict__ outv,
    int K, int N) {
  __shared__ unsigned short As[128 * 32];
  __shared__ unsigned short Bs[128 * 32];
  int tid = threadIdx.x;
  int lane = tid & 63, wave = tid >> 6;
  int mtile = blockIdx.y, ntile = blockIdx.x;
  int rowBase = mtile * 128;
  int colBase = ntile * 128;
  int lda = C1A ? 256 : K;
  int r0 = lane >> 2;            // 0..15 row within 16-row chunk
  int c0 = (lane & 3) * 8;       // k-chunk (elements)
  f32x4 acc[4][4];
#pragma unroll
  for (int i = 0; i < 4; ++i)
#pragma unroll
    for (int j = 0; j < 4; ++j) acc[i][j] = (f32x4)(0.0f);
  int mbase = (wave >> 1) * 64;
  int nbase = (wave & 1) * 64;
  int arow = lane & 15;
  int akk = (lane >> 4) * 8;

  for (int k0 = 0; k0 < K; k0 += 32) {
    size_t arowb; int kin;
    if (C1A) {
      int bb = mtile >> 6, tt = mtile & 63;
      int slab = k0 >> 8;                       // 0,1,2  <-> dt = slab-1
      arowb = (size_t)((bb * 66 + tt + slab) * 128);
      kin = k0 & 255;
    } else {
      arowb = (size_t)rowBase;
      kin = k0;
    }
#pragma unroll
    for (int i = 0; i < 2; ++i) {
      int q = i * 4 + wave;                     // 16-row chunk id, 0..7
      const unsigned short* gp = A + (arowb + q * 16 + r0) * (size_t)lda + kin + c0;
      gload16(gp, &As[q * 512]);
      const unsigned short* gq = Bt + ((size_t)colBase + q * 16 + r0) * (size_t)K + k0 + c0;
      gload16(gq, &Bs[q * 512]);
    }
    __syncthreads();
    short8 af[4], bf[4];
#pragma unroll
    for (int i = 0; i < 4; ++i)
      af[i] = *(const short8*)&As[(mbase + i * 16 + arow) * 32 + akk];
#pragma unroll
    for (int j = 0; j < 4; ++j)
      bf[j] = *(const short8*)&Bs[(nbase + j * 16 + arow) * 32 + akk];
#pragma unroll
    for (int i = 0; i < 4; ++i)
#pragma unroll
      for (int j = 0; j < 4; ++j)
        acc[i][j] = __builtin_amdgcn_mfma_f32_16x16x32_bf16(af[i], bf[j], acc[i][j], 0, 0, 0);
    __syncthreads();
  }

  int crow0 = (lane >> 4) * 4;
  int ccol = lane & 15;
  float gt = (EPI == 3) ? gscal[0] : 0.f;
#pragma unroll
  for (int i = 0; i < 4; ++i) {
#pragma unroll
    for (int j = 0; j < 4; ++j) {
      int col = colBase + nbase + j * 16 + ccol;
      float sc = 1.f, bi = 0.f;
      if (EPI >= 1 && bias) bi = bias[col];
      if ((EPI == 2 || EPI == 3) && scale) sc = scale[col];
#pragma unroll
      for (int r = 0; r < 4; ++r) {
        size_t row = (size_t)rowBase + mbase + i * 16 + crow0 + r;
        size_t idx = row * (size_t)N + col;
        float v = acc[i][j][r];
        if (EPI == 0)      ((unsigned short*)outv)[idx] = f2bf(v);
        else if (EPI == 1) ((unsigned short*)outv)[idx] = f2bf(v + bi);
        else if (EPI == 2) ((unsigned short*)outv)[idx] = f2bf(gelu_f(v * sc + bi));
        else if (EPI == 3) ((float*)outv)[idx] = 2.0f * resf[idx] + gt * (v * sc + bi);
        else if (EPI == 4) ((float*)outv)[idx] = resf[idx] + v + bi;
        else if (EPI == 5) ((float*)outv)[idx] = v + bi;
      }
    }
  }
}

// ---------------- LayerNorm f32 -> bf16, one wave per token ------------------------
template <bool PAD>
__global__ __launch_bounds__(256) void ln256_bf(const float* __restrict__ src,
                                                const float* __restrict__ w,
                                                const float* __restrict__ b,
                                                unsigned short* __restrict__ dst) {
  int lane = threadIdx.x & 63;
  int tok = blockIdx.x * 4 + (threadIdx.x >> 6);
  const float4* row = (const float4*)(src + (size_t)tok * Cn);
  float4 v = row[lane];
  float s  = v.x + v.y + v.z + v.w;
  float s2 = v.x*v.x + v.y*v.y + v.z*v.z + v.w*v.w;
#pragma unroll
  for (int off = 32; off >= 1; off >>= 1) {
    s  += __shfl_xor(s, off, 64);
    s2 += __shfl_xor(s2, off, 64);
  }
  float mean = s * (1.0f / Cn);
  float var = fmaxf(s2 * (1.0f / Cn) - mean * mean, 0.0f);
  float r = rsqrtf(var + EPSF);
  float4 wv = ((const float4*)w)[lane];
  float4 bv = ((const float4*)b)[lane];
  size_t dtok = tok;
  if (PAD) {
    int bb = tok >> 13, tt = (tok >> 7) & 63, e = tok & 127;
    dtok = ((size_t)(bb * 66 + tt + 1)) * 128 + e;
  }
  ushort4 o;
  o.x = f2bf((v.x - mean) * r * wv.x + bv.x);
  o.y = f2bf((v.y - mean) * r * wv.y + bv.y);
  o.z = f2bf((v.z - mean) * r * wv.z + bv.z);
  o.w = f2bf((v.w - mean) * r * wv.w + bv.w);
  *(ushort4*)(dst + dtok * Cn + lane * 4) = o;
}

// ---------------- MFMA spatial attention, one block per (frame, head) --------------
// qkv: [bt*128+e][768]  (q|k|v each 256 wide, head h at h*32)
// maskh: 0.5 * adj  [128*128] f32.   P = maskh*S + 0.5  (== (S*m+1)*0.5)
__global__ __launch_bounds__(256) void attn_mfma(const unsigned short* __restrict__ qkv,
                                                 const float* __restrict__ maskh,
                                                 unsigned short* __restrict__ o) {
  __shared__ unsigned short Qs[128 * 32];
  __shared__ unsigned short Ks[128 * 32];
  __shared__ unsigned short Vt[32 * 136];    // [d][f], padded
  __shared__ unsigned short Ps[128 * 136];   // [e][f], padded
  int tid = threadIdx.x, lane = tid & 63, wave = tid >> 6;
  int h = blockIdx.x & 7, bt = blockIdx.x >> 3;
  size_t gbase = (size_t)bt * 128 * 768 + h * 32;
  // stage Q,K via global_load_lds (each wave: 2 chunks of 16 rows = 1 KB each)
#pragma unroll
  for (int i = 0; i < 2; ++i) {
    int q = wave * 2 + i;
    int row = q * 16 + (lane >> 2);
    int seg = (lane & 3) * 8;
    gload16(qkv + gbase + (size_t)row * 768 + seg, &Qs[q * 512]);
    gload16(qkv + gbase + 256 + (size_t)row * 768 + seg, &Ks[q * 512]);
  }
  // stage V transposed (scalar writes, ~2-way conflicts)
  {
    int e = tid >> 1, dh = (tid & 1) * 16;
    const unsigned short* gv = qkv + gbase + 512 + (size_t)e * 768 + dh;
    short8 v0 = *(const short8*)gv;
    short8 v1 = *(const short8*)(gv + 8);
#pragma unroll
    for (int j = 0; j < 8; ++j) {
      Vt[(dh + j) * 136 + e]     = (unsigned short)v0[j];
      Vt[(dh + 8 + j) * 136 + e] = (unsigned short)v1[j];
    }
  }
  __syncthreads();
  // ---- S = Q K^T for rows [32*wave, 32*wave+32), apply mask, write P to LDS ----
  int arow = lane & 15, akk = (lane >> 4) * 8;
  int crow0 = (lane >> 4) * 4, ccol = lane & 15;
  short8 af0 = *(const short8*)&Qs[(wave * 32 + arow) * 32 + akk];
  short8 af1 = *(const short8*)&Qs[(wave * 32 + 16 + arow) * 32 + akk];
#pragma unroll
  for (int j = 0; j < 8; ++j) {
    short8 bfr = *(const short8*)&Ks[(j * 16 + arow) * 32 + akk];
    f32x4 s0 = __builtin_amdgcn_mfma_f32_16x16x32_bf16(af0, bfr, (f32x4)(0.0f), 0, 0, 0);
    f32x4 s1 = __builtin_amdgcn_mfma_f32_16x16x32_bf16(af1, bfr, (f32x4)(0.0f), 0, 0, 0);
    int f = j * 16 + ccol;
#pragma unroll
    for (int r = 0; r < 4; ++r) {
      int e0 = wave * 32 + crow0 + r;
      int e1 = e0 + 16;
      Ps[e0 * 136 + f] = f2bf(maskh[e0 * 128 + f] * s0[r] + 0.5f);
      Ps[e1 * 136 + f] = f2bf(maskh[e1 * 128 + f] * s1[r] + 0.5f);
    }
  }
  // ---- O = P V for the same rows (wave reads only rows it wrote: no barrier) ----
  f32x4 acc[2][2];
#pragma unroll
  for (int i = 0; i < 2; ++i)
#pragma unroll
    for (int j = 0; j < 2; ++j) acc[i][j] = (f32x4)(0.0f);
#pragma unroll
  for (int k0 = 0; k0 < 128; k0 += 32) {
    short8 a0 = *(const short8*)&Ps[(wave * 32 + arow) * 136 + k0 + akk];
    short8 a1 = *(const short8*)&Ps[(wave * 32 + 16 + arow) * 136 + k0 + akk];
    short8 b0 = *(const short8*)&Vt[arow * 136 + k0 + akk];
    short8 b1 = *(const short8*)&Vt[(16 + arow) * 136 + k0 + akk];
    acc[0][0] = __builtin_amdgcn_mfma_f32_16x16x32_bf16(a0, b0, acc[0][0], 0, 0, 0);
    acc[0][1] = __builtin_amdgcn_mfma_f32_16x16x32_bf16(a0, b1, acc[0][1], 0, 0, 0);
    acc[1][0] = __builtin_amdgcn_mfma_f32_16x16x32_bf16(a1, b0, acc[1][0], 0, 0, 0);
    acc[1][1] = __builtin_amdgcn_mfma_f32_16x16x32_bf16(a1, b1, acc[1][1], 0, 0, 0);
  }
  unsigned short* ob = o + (size_t)bt * 128 * 256 + h * 32;
#pragma unroll
  for (int i = 0; i < 2; ++i)
#pragma unroll
    for (int j = 0; j < 2; ++j)
#pragma unroll
      for (int r = 0; r < 4; ++r) {
        int e = wave * 32 + i * 16 + crow0 + r;
        ob[(size_t)e * 256 + j * 16 + ccol] = f2bf(acc[i][j][r]);
      }
}

// ---------------- residual 1: x1 = x + xs + gamma_s * p2 (f32 out) -----------------
__global__ __launch_bounds__(256) void resid1_kernel(const float* __restrict__ x,
                                                     const unsigned short* __restrict__ xs,
                                                     const unsigned short* __restrict__ p2,
                                                     const float* __restrict__ gs,
                                                     float* __restrict__ x1) {
  size_t i = ((size_t)blockIdx.x * 256 + threadIdx.x) * 4;
  float g = gs[0];
  float4 xv = *(const float4*)(x + i);
  ushort4 s4 = *(const ushort4*)(xs + i);
  ushort4 p4 = *(const ushort4*)(p2 + i);
  float4 r;
  r.x = xv.x + bf2f(s4.x) + g * bf2f(p4.x);
  r.y = xv.y + bf2f(s4.y) + g * bf2f(p4.y);
  r.z = xv.z + bf2f(s4.z) + g * bf2f(p4.z);
  r.w = xv.w + bf2f(s4.w) + g * bf2f(p4.w);
  *(float4*)(x1 + i) = r;
}

// ---------------- prep kernels -----------------------------------------------------
__global__ __launch_bounds__(256) void transcast(const float* __restrict__ src,
                                                 unsigned short* __restrict__ dst,
                                                 int N, int K) {   // dst[n*K+k] = src[k*N+n]
  int idx = blockIdx.x * 256 + threadIdx.x;
  int n = idx / K, k = idx - n * K;
  dst[idx] = f2bf(src[(size_t)k * N + n]);
}
__global__ __launch_bounds__(256) void castbf(const float* __restrict__ s,
                                              unsigned short* __restrict__ d) {
  int i = blockIdx.x * 256 + threadIdx.x;
  d[i] = f2bf(s[i]);
}
__global__ __launch_bounds__(256) void pack_conv1(const float* __restrict__ w1,
                                                  unsigned short* __restrict__ dst) {
  int idx = blockIdx.x * 256 + threadIdx.x;   // 512*768: [h][slab*256+c]
  int hh = idx / 768, kk = idx - hh * 768;
  int slab = kk >> 8, c = kk & 255;
  dst[idx] = f2bf(w1[(size_t)hh * 768 + c * 3 + slab]);
}
__global__ __launch_bounds__(256) void bnfold(const float* __restrict__ w,
                                              const float* __restrict__ bvec,
                                              const float* __restrict__ m,
                                              const float* __restrict__ v,
                                              float* __restrict__ s,
                                              float* __restrict__ o, int n) {
  int i = blockIdx.x * 256 + threadIdx.x;
  if (i < n) {
    float sc = w[i] * rsqrtf(v[i] + EPSF);
    s[i] = sc;
    o[i] = bvec[i] - m[i] * sc;
  }
}
__global__ __launch_bounds__(256) void mask_prep(const int* __restrict__ adj,
                                                 float* __restrict__ maskh) {
  int i = blockIdx.x * 256 + threadIdx.x;   // 16384
  maskh[i] = 0.5f * (float)adj[i];
}
__global__ __launch_bounds__(256) void zero_pad(unsigned short* __restrict__ xt) {
  int idx = blockIdx.x * 256 + threadIdx.x;   // 8 b * 2 rows * 128*256
  int bb = idx >> 16;
  int rem = idx & 65535;
  int which = rem >> 15;      // 0 -> t_pad 0, 1 -> t_pad 65
  int off = rem & 32767;
  size_t base = ((size_t)(bb * 66 + which * 65)) * 128 * 256;
  xt[base + off] = 0;
}

// ---------------- host-side launch --------------------------------------------------
extern "C" void kernel_launch(void* const* d_in, const int* in_sizes, int n_in,
                              void* d_out, int out_size, void* d_ws, size_t ws_size,
                              hipStream_t stream) {
  (void)in_sizes; (void)n_in; (void)out_size; (void)ws_size;
  const float* x       = (const float*)d_in[0];
  const int*   adj     = (const int*)  d_in[1];
  const float* n1_w    = (const float*)d_in[2];
  const float* n1_b    = (const float*)d_in[3];
  const float* q_w     = (const float*)d_in[4];
  const float* k_w     = (const float*)d_in[5];
  const float* v_w     = (const float*)d_in[6];
  const float* proj_w  = (const float*)d_in[7];
  const float* proj_b  = (const float*)d_in[8];
  const float* on_w    = (const float*)d_in[9];
  const float* on_b    = (const float*)d_in[10];
  const float* gamma_s = (const float*)d_in[11];
  const float* conv1_w = (const float*)d_in[12];
  const float* bn1_w   = (const float*)d_in[13];
  const float* bn1_b   = (const float*)d_in[14];
  const float* bn1_m   = (const float*)d_in[15];
  const float* bn1_v   = (const float*)d_in[16];
  const float* conv2_w = (const float*)d_in[17];
  const float* bn2_w   = (const float*)d_in[18];
  const float* bn2_b   = (const float*)d_in[19];
  const float* bn2_m   = (const float*)d_in[20];
  const float* bn2_v   = (const float*)d_in[21];
  const float* tn_w    = (const float*)d_in[22];
  const float* tn_b    = (const float*)d_in[23];
  const float* gamma_t = (const float*)d_in[24];
  const float* n3_w    = (const float*)d_in[25];
  const float* n3_b    = (const float*)d_in[26];
  const float* fc1_w   = (const float*)d_in[27];
  const float* fc1_b   = (const float*)d_in[28];
  const float* fc2_w   = (const float*)d_in[29];
  const float* fc2_b   = (const float*)d_in[30];
  float* O = (float*)d_out;

  const size_t MB = 1024 * 1024;
  char* wsb = (char*)d_ws;
  // live-range overlaid buffers (peak ~170 MB)
  unsigned short* qkvb = (unsigned short*)(wsb + 0);        // 96 MB  [qkv gemm -> attn]
  float*          pjo  = (float*)(wsb + 0);                 // 64 MB  [proj out f32]
  float*          x1b  = (float*)(wsb + 0);                 // 64 MB  [resid1 -> conv2]
  unsigned short* xmb  = (unsigned short*)(wsb + 0);        // 32 MB  [ln3 -> fc1]
  unsigned short* hb   = (unsigned short*)(wsb + 32 * MB);  // 128 MB [fc1 -> fc2]
  unsigned short* xtp  = (unsigned short*)(wsb + 64 * MB);  // 33 MB  [ln_t -> conv1]
  unsigned short* xsb  = (unsigned short*)(wsb + 96 * MB);  // 32 MB  [ln1 -> resid1]
  unsigned short* oat  = (unsigned short*)(wsb + 128 * MB); // 32 MB  [attn -> proj]
  unsigned short* p2b  = (unsigned short*)(wsb + 128 * MB); // 32 MB  [ln_o -> resid1]
  unsigned short* y1b  = (unsigned short*)(wsb + 100 * MB); // 64 MB  [conv1 -> conv2]
  char* wp = wsb + 164 * MB;
  unsigned short* Wqkv = (unsigned short*)wp;  wp += 768 * 256 * 2;
  unsigned short* PjT  = (unsigned short*)wp;  wp += 256 * 256 * 2;
  unsigned short* W1t  = (unsigned short*)wp;  wp += 512 * 768 * 2;
  unsigned short* W2t  = (unsigned short*)wp;  wp += 256 * 512 * 2;
  unsigned short* F1t  = (unsigned short*)wp;  wp += 1024 * 256 * 2;
  unsigned short* F2t  = (unsigned short*)wp;  wp += 256 * 1024 * 2;
  float* s1 = (float*)wp; wp += 512 * 4;
  float* o1 = (float*)wp; wp += 512 * 4;
  float* s2 = (float*)wp; wp += 256 * 4;
  float* o2 = (float*)wp; wp += 256 * 4;
  float* maskh = (float*)wp; wp += 16384 * 4;

  // ---- prep (cheap, once per launch) ----
  transcast<<<768 * 256 / 256, 256, 0, stream>>>(q_w, Wqkv, 256, 256);
  transcast<<<768 * 256 / 256, 256, 0, stream>>>(k_w, Wqkv + 256 * 256, 256, 256);
  transcast<<<768 * 256 / 256, 256, 0, stream>>>(v_w, Wqkv + 512 * 256, 256, 256);
  transcast<<<256 * 256 / 256, 256, 0, stream>>>(proj_w, PjT, 256, 256);
  pack_conv1<<<512 * 768 / 256, 256, 0, stream>>>(conv1_w, W1t);
  castbf<<<256 * 512 / 256, 256, 0, stream>>>(conv2_w, W2t);   // already [C][H] = [N][K]
  transcast<<<1024 * 256 / 256, 256, 0, stream>>>(fc1_w, F1t, 1024, 256);
  transcast<<<256 * 1024 / 256, 256, 0, stream>>>(fc2_w, F2t, 256, 1024);
  bnfold<<<2, 256, 0, stream>>>(bn1_w, bn1_b, bn1_m, bn1_v, s1, o1, 512);
  bnfold<<<1, 256, 0, stream>>>(bn2_w, bn2_b, bn2_m, bn2_v, s2, o2, 256);
  mask_prep<<<64, 256, 0, stream>>>(adj, maskh);
  zero_pad<<<524288 / 256, 256, 0, stream>>>(xtp);

  // ---- spatial attention branch ----
  ln256_bf<false><<<NTOK / 4, 256, 0, stream>>>(x, n1_w, n1_b, xsb);
  mfma_gemm<0, false><<<dim3(6, 512), 256, 0, stream>>>(xsb, Wqkv, nullptr, nullptr, nullptr, nullptr, qkvb, 256, 768);
  attn_mfma<<<Bn * Tn * NHd, 256, 0, stream>>>(qkvb, maskh, oat);
  mfma_gemm<5, false><<<dim3(2, 512), 256, 0, stream>>>(oat, PjT, nullptr, proj_b, nullptr, nullptr, pjo, 256, 256);
  ln256_bf<false><<<NTOK / 4, 256, 0, stream>>>(pjo, on_w, on_b, p2b);
  resid1_kernel<<<(int)(SZ / (4 * 256)), 256, 0, stream>>>(x, xsb, p2b, gamma_s, x1b);

  // ---- temporal conv branch ----
  ln256_bf<true><<<NTOK / 4, 256, 0, stream>>>(x1b, tn_w, tn_b, xtp);
  mfma_gemm<2, true><<<dim3(4, 512), 256, 0, stream>>>(xtp, W1t, s1, o1, nullptr, nullptr, y1b, 768, 512);
  mfma_gemm<3, false><<<dim3(2, 512), 256, 0, stream>>>(y1b, W2t, s2, o2, x1b, gamma_t, O, 512, 256);

  // ---- MLP ----
  ln256_bf<false><<<NTOK / 4, 256, 0, stream>>>(O, n3_w, n3_b, xmb);
  mfma_gemm<2, false><<<dim3(8, 512), 256, 0, stream>>>(xmb, F1t, nullptr, fc1_b, nullptr, nullptr, hb, 256, 1024);
  mfma_gemm<4, false><<<dim3(2, 512), 256, 0, stream>>>(hb, F2t, nullptr, fc2_b, O, nullptr, O, 1024, 256);
}